// Round 1
// baseline (57.573 us; speedup 1.0000x reference)
//
#include <hip/hip_runtime.h>

#define EE 1024
#define LN_EPS 1e-5f

// ---------------- leaf: LN+ReLU over gathered emb rows ----------------
__global__ __launch_bounds__(256) void leaf_kernel(
    const int* __restrict__ word_ids, const float* __restrict__ emb,
    const float* __restrict__ gamma, const float* __restrict__ beta,
    float* __restrict__ h) {
  const int node = blockIdx.x;                 // leaf 0..1023
  const int t = threadIdx.x;                   // 256 threads, 4 elems each
  const int wid = word_ids[1023 + node];
  const float4* x4 = (const float4*)(emb + (size_t)wid * EE);
  float4 v = x4[t];

  float s  = v.x + v.y + v.z + v.w;
  float ss = v.x * v.x + v.y * v.y + v.z * v.z + v.w * v.w;

  __shared__ float red[8];
  #pragma unroll
  for (int off = 32; off; off >>= 1) {
    s  += __shfl_xor(s, off);
    ss += __shfl_xor(ss, off);
  }
  const int lane = t & 63, wv = t >> 6;
  if (lane == 0) { red[wv] = s; red[4 + wv] = ss; }
  __syncthreads();
  if (t == 0) {
    float S  = red[0] + red[1] + red[2] + red[3];
    float SS = red[4] + red[5] + red[6] + red[7];
    float mu = S * (1.0f / EE);
    float var = SS * (1.0f / EE) - mu * mu;
    red[0] = mu;
    red[1] = rsqrtf(var + LN_EPS);
  }
  __syncthreads();
  const float mu = red[0], rs = red[1];

  float4 g  = ((const float4*)gamma)[t];
  float4 bt = ((const float4*)beta)[t];
  float4 y;
  y.x = fmaxf((v.x - mu) * rs * g.x + bt.x, 0.0f);
  y.y = fmaxf((v.y - mu) * rs * g.y + bt.y, 0.0f);
  y.z = fmaxf((v.z - mu) * rs * g.z + bt.z, 0.0f);
  y.w = fmaxf((v.w - mu) * rs * g.w + bt.w, 0.0f);
  ((float4*)(h + (size_t)node * EE))[t] = y;
}

// ------------- internal node: x = (L@R@C)@Ww.T + Wb; LN+ReLU -------------
__global__ __launch_bounds__(256) void node_kernel(
    const int* __restrict__ word_ids, const float* __restrict__ emb,
    const float* __restrict__ Ww, const float* __restrict__ Wb,
    const float* __restrict__ gamma, const float* __restrict__ beta,
    const float* __restrict__ h_prev, float* __restrict__ h_cur, int sIdx) {
  const int b = blockIdx.x;
  const int t = threadIdx.x;

  __shared__ float L[32][32];   // left child, later reused as T2
  __shared__ float R[32][32];   // right child
  __shared__ float C[32][32];   // current emb
  __shared__ float T1[32][32];  // L@R
  __shared__ float Wt[32][32];  // Ww transposed: Wt[l][m] = Ww[m][l]
  __shared__ float red[8];

  const int wid = word_ids[sIdx + b];
  ((float4*)&L[0][0])[t] = ((const float4*)(h_prev + (size_t)(2 * b) * EE))[t];
  ((float4*)&R[0][0])[t] = ((const float4*)(h_prev + (size_t)(2 * b + 1) * EE))[t];
  ((float4*)&C[0][0])[t] = ((const float4*)(emb + (size_t)wid * EE))[t];
  {
    float4 w = ((const float4*)Ww)[t];
    int p = t * 4;
    int m = p >> 5;          // row of Ww
    int l = p & 31;          // col of Ww
    Wt[l + 0][m] = w.x;
    Wt[l + 1][m] = w.y;
    Wt[l + 2][m] = w.z;
    Wt[l + 3][m] = w.w;
  }
  __syncthreads();

  const int j = t & 31;
  const int i0 = (t >> 5) * 4;  // rows i0..i0+3

  // T1 = L @ R
  float a0 = 0.f, a1 = 0.f, a2 = 0.f, a3 = 0.f;
  #pragma unroll
  for (int k = 0; k < 32; ++k) {
    float bb = R[k][j];
    a0 = fmaf(L[i0 + 0][k], bb, a0);
    a1 = fmaf(L[i0 + 1][k], bb, a1);
    a2 = fmaf(L[i0 + 2][k], bb, a2);
    a3 = fmaf(L[i0 + 3][k], bb, a3);
  }
  T1[i0 + 0][j] = a0; T1[i0 + 1][j] = a1;
  T1[i0 + 2][j] = a2; T1[i0 + 3][j] = a3;
  __syncthreads();

  // T2 = T1 @ C  (store into R, which is no longer needed)
  a0 = a1 = a2 = a3 = 0.f;
  #pragma unroll
  for (int k = 0; k < 32; ++k) {
    float bb = C[k][j];
    a0 = fmaf(T1[i0 + 0][k], bb, a0);
    a1 = fmaf(T1[i0 + 1][k], bb, a1);
    a2 = fmaf(T1[i0 + 2][k], bb, a2);
    a3 = fmaf(T1[i0 + 3][k], bb, a3);
  }
  __syncthreads();  // all reads of R (first matmul) long done; reads of T1 done
  R[i0 + 0][j] = a0; R[i0 + 1][j] = a1;
  R[i0 + 2][j] = a2; R[i0 + 3][j] = a3;
  __syncthreads();

  // X = T2 @ Ww.T + Wb :  X[i][j] = sum_l T2[i][l] * Wt[l][j] + Wb[j]
  const float wb = Wb[j];
  a0 = a1 = a2 = a3 = wb;
  #pragma unroll
  for (int l = 0; l < 32; ++l) {
    float bb = Wt[l][j];
    a0 = fmaf(R[i0 + 0][l], bb, a0);
    a1 = fmaf(R[i0 + 1][l], bb, a1);
    a2 = fmaf(R[i0 + 2][l], bb, a2);
    a3 = fmaf(R[i0 + 3][l], bb, a3);
  }

  // LayerNorm over all 1024 elements + gamma/beta + ReLU
  float s  = a0 + a1 + a2 + a3;
  float ss = a0 * a0 + a1 * a1 + a2 * a2 + a3 * a3;
  #pragma unroll
  for (int off = 32; off; off >>= 1) {
    s  += __shfl_xor(s, off);
    ss += __shfl_xor(ss, off);
  }
  const int lane = t & 63, wv = t >> 6;
  if (lane == 0) { red[wv] = s; red[4 + wv] = ss; }
  __syncthreads();
  if (t == 0) {
    float S  = red[0] + red[1] + red[2] + red[3];
    float SS = red[4] + red[5] + red[6] + red[7];
    float mu = S * (1.0f / EE);
    float var = SS * (1.0f / EE) - mu * mu;
    red[0] = mu;
    red[1] = rsqrtf(var + LN_EPS);
  }
  __syncthreads();
  const float mu = red[0], rs = red[1];

  float* hout = h_cur + (size_t)b * EE;
  {
    int idx = (i0 + 0) * 32 + j;
    hout[idx] = fmaxf((a0 - mu) * rs * gamma[idx] + beta[idx], 0.0f);
    idx = (i0 + 1) * 32 + j;
    hout[idx] = fmaxf((a1 - mu) * rs * gamma[idx] + beta[idx], 0.0f);
    idx = (i0 + 2) * 32 + j;
    hout[idx] = fmaxf((a2 - mu) * rs * gamma[idx] + beta[idx], 0.0f);
    idx = (i0 + 3) * 32 + j;
    hout[idx] = fmaxf((a3 - mu) * rs * gamma[idx] + beta[idx], 0.0f);
  }
}

// ---------------- head: logits, argmax, log-softmax loss ----------------
__global__ __launch_bounds__(256) void head_kernel(
    const float* __restrict__ root, const float* __restrict__ Pw,
    const float* __restrict__ Pb, const int* __restrict__ label,
    float* __restrict__ out) {
  const int t = threadIdx.x;
  __shared__ float lg[10];
  if (t < 10) lg[t] = 0.0f;
  __syncthreads();

  float4 r4 = ((const float4*)root)[t];
  float p[10];
  #pragma unroll
  for (int c = 0; c < 10; ++c) {
    float4 w = ((const float4*)(Pw + (size_t)c * EE))[t];
    p[c] = r4.x * w.x + r4.y * w.y + r4.z * w.z + r4.w * w.w;
  }
  #pragma unroll
  for (int c = 0; c < 10; ++c) {
    #pragma unroll
    for (int off = 32; off; off >>= 1) p[c] += __shfl_xor(p[c], off);
  }
  if ((t & 63) == 0) {
    #pragma unroll
    for (int c = 0; c < 10; ++c) atomicAdd(&lg[c], p[c]);
  }
  __syncthreads();
  if (t == 0) {
    float logits[10];
    #pragma unroll
    for (int c = 0; c < 10; ++c) logits[c] = lg[c] + Pb[c];
    float m = logits[0];
    int am = 0;
    #pragma unroll
    for (int c = 1; c < 10; ++c)
      if (logits[c] > m) { m = logits[c]; am = c; }
    float sum = 0.0f;
    #pragma unroll
    for (int c = 0; c < 10; ++c) sum += expf(logits[c] - m);
    int lb = label[0];
    float loss = -(logits[lb] - m - logf(sum));
    out[0] = (float)am;
    out[1] = loss;
  }
}

extern "C" void kernel_launch(void* const* d_in, const int* in_sizes, int n_in,
                              void* d_out, int out_size, void* d_ws, size_t ws_size,
                              hipStream_t stream) {
  const int*   word_ids = (const int*)d_in[0];
  const int*   label    = (const int*)d_in[1];
  const float* emb      = (const float*)d_in[2];
  const float* Ww       = (const float*)d_in[3];
  const float* Wb       = (const float*)d_in[4];
  const float* gamma    = (const float*)d_in[5];
  const float* beta     = (const float*)d_in[6];
  const float* Pw       = (const float*)d_in[7];
  const float* Pb       = (const float*)d_in[8];
  float* out = (float*)d_out;

  float* hA = (float*)d_ws;
  float* hB = hA + 1024 * 1024;

  leaf_kernel<<<1024, 256, 0, stream>>>(word_ids, emb, gamma, beta, hA);

  const float* prev = hA;
  float* cur = hB;
  for (int d = 9; d >= 0; --d) {
    int sIdx = (1 << d) - 1;
    node_kernel<<<(1 << d), 256, 0, stream>>>(word_ids, emb, Ww, Wb, gamma,
                                              beta, prev, cur, sIdx);
    float* tmp = cur;
    cur = (float*)prev;
    prev = tmp;
  }

  head_kernel<<<1, 256, 0, stream>>>(prev, Pw, Pb, label, out);
}